// Round 1
// baseline (296.432 us; speedup 1.0000x reference)
//
#include <hip/hip_runtime.h>
#include <hip/hip_bf16.h>

#define B_SZ 4
#define SEQ 8192
#define DIM 512
#define HEADS 8
#define DH 64
#define INNER 512
#define QKV_COLS 1536
#define M_TOT (B_SZ * SEQ)   // 32768
#define BHN (B_SZ * HEADS)   // 32

typedef __bf16 bf16x8 __attribute__((ext_vector_type(8)));
typedef __bf16 bf16x4 __attribute__((ext_vector_type(4)));
typedef float f32x4 __attribute__((ext_vector_type(4)));

__device__ __forceinline__ float elu1(float x) {
    return x > 0.f ? x + 1.f : __expf(x);   // elu(x)+1 = e^x for x<0
}

// ---------------- K0: convert + transpose weights to bf16 B^T layout ----------
__global__ void convert_weights(const float* __restrict__ w_qkv,
                                const float* __restrict__ w_out,
                                __bf16* __restrict__ wqkv_t,   // [1536][512]
                                __bf16* __restrict__ wout_t) { // [512][512]
    int id = blockIdx.x * 256 + threadIdx.x;
    if (id < QKV_COLS * DIM) {
        int n = id / DIM, k = id % DIM;
        wqkv_t[id] = (__bf16)w_qkv[k * QKV_COLS + n];
    } else {
        int id2 = id - QKV_COLS * DIM;
        if (id2 < INNER * DIM) {
            int n = id2 / DIM, k = id2 % DIM;
            wout_t[id2] = (__bf16)w_out[k * DIM + n];
        }
    }
}

// ---------------- K1: qkv GEMM (fp32 A staged->bf16), fused elu, scatter ------
__launch_bounds__(256, 2)
__global__ void gemm_qkv(const float* __restrict__ x,
                         const __bf16* __restrict__ wqkv_t,
                         __bf16* __restrict__ q_ws,    // [b,h,n,dh]
                         __bf16* __restrict__ kT_ws,   // [b,h,dh,n]
                         __bf16* __restrict__ vT_ws) { // [b,h,dh,n]
    __shared__ __attribute__((aligned(16))) __bf16 As[128][40];
    __shared__ __attribute__((aligned(16))) __bf16 Bs[128][40];
    const int tid = threadIdx.x;
    const int wid = tid >> 6;
    const int lane = tid & 63;
    const int wm = wid >> 1, wn = wid & 1;
    const int lq = lane >> 4, lr = lane & 15;
    const int m0 = blockIdx.x * 128;
    const int n0 = blockIdx.y * 128;

    f32x4 acc[4][4] = {};

    for (int kb = 0; kb < DIM; kb += 32) {
        // stage A tile 128x32 (fp32 -> bf16)
#pragma unroll
        for (int t = 0; t < 4; ++t) {
            int c = tid + t * 256;            // 1024 chunks of 4 floats
            int row = c >> 3, kc = (c & 7) * 4;
            float4 f = *reinterpret_cast<const float4*>(
                &x[(size_t)(m0 + row) * DIM + kb + kc]);
            bf16x4 h = {(__bf16)f.x, (__bf16)f.y, (__bf16)f.z, (__bf16)f.w};
            *reinterpret_cast<bf16x4*>(&As[row][kc]) = h;
        }
        // stage B tile 128x32 (bf16)
#pragma unroll
        for (int t = 0; t < 2; ++t) {
            int c = tid + t * 256;            // 512 chunks of 8 bf16
            int row = c >> 2, kc = (c & 3) * 8;
            *reinterpret_cast<bf16x8*>(&Bs[row][kc]) =
                *reinterpret_cast<const bf16x8*>(
                    &wqkv_t[(size_t)(n0 + row) * DIM + kb + kc]);
        }
        __syncthreads();
        bf16x8 af[4], bfv[4];
#pragma unroll
        for (int i = 0; i < 4; ++i)
            af[i] = *reinterpret_cast<const bf16x8*>(&As[wm * 64 + i * 16 + lr][lq * 8]);
#pragma unroll
        for (int i = 0; i < 4; ++i)
            bfv[i] = *reinterpret_cast<const bf16x8*>(&Bs[wn * 64 + i * 16 + lr][lq * 8]);
#pragma unroll
        for (int i = 0; i < 4; ++i)
#pragma unroll
            for (int j = 0; j < 4; ++j)
                acc[i][j] = __builtin_amdgcn_mfma_f32_16x16x32_bf16(
                    af[i], bfv[j], acc[i][j], 0, 0, 0);
        __syncthreads();
    }

    // epilogue: split into q / k / v with elu+1 on q,k; k,v transposed
#pragma unroll
    for (int j = 0; j < 4; ++j) {
        int col = n0 + wn * 64 + j * 16 + lr;      // 0..1535
        int which = col / INNER;                   // 0=q 1=k 2=v (wave-uniform)
        int within = col % INNER;
        int h = within / DH, d = within % DH;
#pragma unroll
        for (int i = 0; i < 4; ++i) {
            int row_base = m0 + wm * 64 + i * 16 + lq * 4;
            int b = row_base / SEQ;
            int seq = row_base % SEQ;
            if (which == 0) {
                size_t base = ((size_t)(b * HEADS + h) * SEQ) * DH + d;
#pragma unroll
                for (int r = 0; r < 4; ++r)
                    q_ws[base + (size_t)(seq + r) * DH] = (__bf16)elu1(acc[i][j][r]);
            } else {
                __bf16* dst = (which == 1) ? kT_ws : vT_ws;
                size_t base = ((size_t)(b * HEADS + h) * DH + d) * SEQ + seq;
                bf16x4 h4;
#pragma unroll
                for (int r = 0; r < 4; ++r) {
                    float v = acc[i][j][r];
                    h4[r] = (__bf16)((which == 1) ? elu1(v) : v);
                }
                *reinterpret_cast<bf16x4*>(&dst[base]) = h4;  // 4 consecutive n
            }
        }
    }
}

// ---------------- K2: kv^T[bh][m][d] = sum_n K^T[d][n] * V[n][m] --------------
__launch_bounds__(256, 2)
__global__ void kv_reduce(const __bf16* __restrict__ kT,
                          const __bf16* __restrict__ vT,
                          float* __restrict__ kv_t) {   // [bh][m][d] fp32
    __shared__ __attribute__((aligned(16))) __bf16 Ks[64][136];
    __shared__ __attribute__((aligned(16))) __bf16 Vs[64][136];
    const int tid = threadIdx.x;
    const int wid = tid >> 6;
    const int lane = tid & 63;
    const int lq = lane >> 4, lr = lane & 15;
    const int bh = blockIdx.y;
    const int n0 = blockIdx.x * 512;
    const size_t base = (size_t)bh * DH * SEQ;
    f32x4 acc[4] = {};

    for (int ch = 0; ch < 4; ++ch) {
        int nc = n0 + ch * 128;
#pragma unroll
        for (int t = 0; t < 4; ++t) {
            int c = tid + t * 256;              // 1024 chunks: 64 rows x 16
            int row = c >> 4, kc = (c & 15) * 8;
            *reinterpret_cast<bf16x8*>(&Ks[row][kc]) =
                *reinterpret_cast<const bf16x8*>(&kT[base + (size_t)row * SEQ + nc + kc]);
            *reinterpret_cast<bf16x8*>(&Vs[row][kc]) =
                *reinterpret_cast<const bf16x8*>(&vT[base + (size_t)row * SEQ + nc + kc]);
        }
        __syncthreads();
#pragma unroll
        for (int ks = 0; ks < 4; ++ks) {
            bf16x8 a = *reinterpret_cast<const bf16x8*>(&Ks[wid * 16 + lr][ks * 32 + lq * 8]);
#pragma unroll
            for (int j = 0; j < 4; ++j) {
                bf16x8 b = *reinterpret_cast<const bf16x8*>(&Vs[j * 16 + lr][ks * 32 + lq * 8]);
                acc[j] = __builtin_amdgcn_mfma_f32_16x16x32_bf16(a, b, acc[j], 0, 0, 0);
            }
        }
        __syncthreads();
    }
    float* dst = kv_t + (size_t)bh * DH * DH;
#pragma unroll
    for (int j = 0; j < 4; ++j) {
        int m = j * 16 + lr;
#pragma unroll
        for (int r = 0; r < 4; ++r) {
            int d = wid * 16 + lq * 4 + r;
            atomicAdd(&dst[m * DH + d], acc[j][r]);
        }
    }
}

// ---------------- K3: ksum[bh*64+d] = sum_n K^T[d][n] -------------------------
__global__ void ksum_kernel(const __bf16* __restrict__ kT, float* __restrict__ ksum) {
    const int wid = threadIdx.x >> 6, lane = threadIdx.x & 63;
    const int row = blockIdx.x * 4 + wid;         // 0..2047
    const __bf16* src = kT + (size_t)row * SEQ;
    float s = 0.f;
    for (int i = 0; i < 16; ++i) {
        bf16x8 v = *reinterpret_cast<const bf16x8*>(&src[(i * 64 + lane) * 8]);
#pragma unroll
        for (int j = 0; j < 8; ++j) s += (float)v[j];
    }
#pragma unroll
    for (int off = 32; off > 0; off >>= 1) s += __shfl_down(s, off, 64);
    if (lane == 0) ksum[row] = s;
}

// ---------------- K4: attn[b][n][h*64+m] = z * (q @ kv) -----------------------
__launch_bounds__(256, 2)
__global__ void attn_kernel(const __bf16* __restrict__ q_ws,
                            const float* __restrict__ kv_t,
                            const float* __restrict__ ksum,
                            __bf16* __restrict__ attn) {
    __shared__ __attribute__((aligned(16))) __bf16 Qs[128][72];
    __shared__ __attribute__((aligned(16))) __bf16 KVs[64][72];
    __shared__ float zs[128];
    __shared__ float ks_s[64];
    const int tid = threadIdx.x;
    const int wid = tid >> 6, lane = tid & 63;
    const int lq = lane >> 4, lr = lane & 15;
    const int bh = blockIdx.y;
    const int b = bh >> 3, h = bh & 7;
    const int n0 = blockIdx.x * 128;
    const size_t qbase = ((size_t)bh * SEQ + n0) * DH;

#pragma unroll
    for (int t = 0; t < 4; ++t) {
        int c = tid + t * 256;                    // 128 rows x 8 chunks
        int row = c >> 3, kc = (c & 7) * 8;
        *reinterpret_cast<bf16x8*>(&Qs[row][kc]) =
            *reinterpret_cast<const bf16x8*>(&q_ws[qbase + (size_t)row * DH + kc]);
    }
    const float* kvsrc = kv_t + (size_t)bh * DH * DH;
#pragma unroll
    for (int t = 0; t < 4; ++t) {
        int c = tid + t * 256;                    // 64 rows x 16 float4
        int m = c >> 4, dc = (c & 15) * 4;
        float4 f = *reinterpret_cast<const float4*>(&kvsrc[m * DH + dc]);
        bf16x4 h4 = {(__bf16)f.x, (__bf16)f.y, (__bf16)f.z, (__bf16)f.w};
        *reinterpret_cast<bf16x4*>(&KVs[m][dc]) = h4;
    }
    if (tid < 64) ks_s[tid] = ksum[bh * DH + tid];
    __syncthreads();
    {
        int row = tid >> 1, part = tid & 1;
        float s = 0.f;
#pragma unroll
        for (int j = 0; j < 32; ++j)
            s += (float)Qs[row][part * 32 + j] * ks_s[part * 32 + j];
        s += __shfl_xor(s, 1, 64);
        if (part == 0) zs[row] = 1.f / (s + 1e-6f);
    }
    __syncthreads();

    f32x4 acc[2][4] = {};
#pragma unroll
    for (int ks = 0; ks < 2; ++ks) {
        bf16x8 a0 = *reinterpret_cast<const bf16x8*>(&Qs[wid * 32 + lr][ks * 32 + lq * 8]);
        bf16x8 a1 = *reinterpret_cast<const bf16x8*>(&Qs[wid * 32 + 16 + lr][ks * 32 + lq * 8]);
#pragma unroll
        for (int j = 0; j < 4; ++j) {
            bf16x8 bfr = *reinterpret_cast<const bf16x8*>(&KVs[j * 16 + lr][ks * 32 + lq * 8]);
            acc[0][j] = __builtin_amdgcn_mfma_f32_16x16x32_bf16(a0, bfr, acc[0][j], 0, 0, 0);
            acc[1][j] = __builtin_amdgcn_mfma_f32_16x16x32_bf16(a1, bfr, acc[1][j], 0, 0, 0);
        }
    }
#pragma unroll
    for (int mt = 0; mt < 2; ++mt)
#pragma unroll
        for (int j = 0; j < 4; ++j) {
            int m = j * 16 + lr;
#pragma unroll
            for (int r = 0; r < 4; ++r) {
                int row = wid * 32 + mt * 16 + lq * 4 + r;
                float v = acc[mt][j][r] * zs[row];
                attn[((size_t)(b * SEQ + n0 + row)) * INNER + h * DH + m] = (__bf16)v;
            }
        }
}

// ---------------- K5: out = attn @ w_out + b_out (fp32 out) -------------------
__launch_bounds__(256, 2)
__global__ void gemm_out(const __bf16* __restrict__ attn,
                         const __bf16* __restrict__ wout_t,
                         const float* __restrict__ b_out,
                         float* __restrict__ out) {
    __shared__ __attribute__((aligned(16))) __bf16 As[128][40];
    __shared__ __attribute__((aligned(16))) __bf16 Bs[128][40];
    const int tid = threadIdx.x;
    const int wid = tid >> 6;
    const int lane = tid & 63;
    const int wm = wid >> 1, wn = wid & 1;
    const int lq = lane >> 4, lr = lane & 15;
    const int m0 = blockIdx.x * 128;
    const int n0 = blockIdx.y * 128;

    f32x4 acc[4][4] = {};

    for (int kb = 0; kb < INNER; kb += 32) {
#pragma unroll
        for (int t = 0; t < 2; ++t) {
            int c = tid + t * 256;
            int row = c >> 2, kc = (c & 3) * 8;
            *reinterpret_cast<bf16x8*>(&As[row][kc]) =
                *reinterpret_cast<const bf16x8*>(
                    &attn[(size_t)(m0 + row) * INNER + kb + kc]);
        }
#pragma unroll
        for (int t = 0; t < 2; ++t) {
            int c = tid + t * 256;
            int row = c >> 2, kc = (c & 3) * 8;
            *reinterpret_cast<bf16x8*>(&Bs[row][kc]) =
                *reinterpret_cast<const bf16x8*>(
                    &wout_t[(size_t)(n0 + row) * INNER + kb + kc]);
        }
        __syncthreads();
        bf16x8 af[4], bfv[4];
#pragma unroll
        for (int i = 0; i < 4; ++i)
            af[i] = *reinterpret_cast<const bf16x8*>(&As[wm * 64 + i * 16 + lr][lq * 8]);
#pragma unroll
        for (int i = 0; i < 4; ++i)
            bfv[i] = *reinterpret_cast<const bf16x8*>(&Bs[wn * 64 + i * 16 + lr][lq * 8]);
#pragma unroll
        for (int i = 0; i < 4; ++i)
#pragma unroll
            for (int j = 0; j < 4; ++j)
                acc[i][j] = __builtin_amdgcn_mfma_f32_16x16x32_bf16(
                    af[i], bfv[j], acc[i][j], 0, 0, 0);
        __syncthreads();
    }

#pragma unroll
    for (int j = 0; j < 4; ++j) {
        int col = n0 + wn * 64 + j * 16 + lr;
        float bias = b_out[col];
#pragma unroll
        for (int i = 0; i < 4; ++i) {
            int row = m0 + wm * 64 + i * 16 + lq * 4;
#pragma unroll
            for (int r = 0; r < 4; ++r)
                out[(size_t)(row + r) * DIM + col] = acc[i][j][r] + bias;
        }
    }
}

// ------------------------------------------------------------------------------
extern "C" void kernel_launch(void* const* d_in, const int* in_sizes, int n_in,
                              void* d_out, int out_size, void* d_ws, size_t ws_size,
                              hipStream_t stream) {
    (void)in_sizes; (void)n_in; (void)out_size; (void)ws_size;
    const float* x     = (const float*)d_in[0];
    const float* w_qkv = (const float*)d_in[1];
    const float* w_out = (const float*)d_in[2];
    const float* b_out = (const float*)d_in[3];
    float* out = (float*)d_out;

    char* ws = (char*)d_ws;
    size_t off = 0;
    auto alloc = [&](size_t bytes) {
        char* p = ws + off;
        off += (bytes + 255) & ~(size_t)255;
        return p;
    };
    __bf16* q_ws   = (__bf16*)alloc((size_t)BHN * SEQ * DH * 2);
    __bf16* kT_ws  = (__bf16*)alloc((size_t)BHN * SEQ * DH * 2);
    __bf16* vT_ws  = (__bf16*)alloc((size_t)BHN * SEQ * DH * 2);
    __bf16* attn   = (__bf16*)alloc((size_t)M_TOT * INNER * 2);
    float*  kv_t   = (float*)alloc((size_t)BHN * DH * DH * 4 + (size_t)BHN * DH * 4);
    float*  ksum   = kv_t + (size_t)BHN * DH * DH;
    __bf16* wqkv_t = (__bf16*)alloc((size_t)QKV_COLS * DIM * 2);
    __bf16* wout_t = (__bf16*)alloc((size_t)INNER * DIM * 2);

    hipMemsetAsync(kv_t, 0, (size_t)BHN * DH * DH * 4 + (size_t)BHN * DH * 4, stream);
    convert_weights<<<dim3((QKV_COLS * DIM + INNER * DIM) / 256), 256, 0, stream>>>(
        w_qkv, w_out, wqkv_t, wout_t);
    gemm_qkv<<<dim3(M_TOT / 128, QKV_COLS / 128), 256, 0, stream>>>(
        x, wqkv_t, q_ws, kT_ws, vT_ws);
    kv_reduce<<<dim3(16, BHN), 256, 0, stream>>>(kT_ws, vT_ws, kv_t);
    ksum_kernel<<<dim3(BHN * DH / 4), 256, 0, stream>>>(kT_ws, ksum);
    attn_kernel<<<dim3(SEQ / 128, BHN), 256, 0, stream>>>(q_ws, kv_t, ksum, attn);
    gemm_out<<<dim3(M_TOT / 128, DIM / 128), 256, 0, stream>>>(attn, wout_t, b_out, out);
}